// Round 8
// baseline (373.422 us; speedup 1.0000x reference)
//
#include <hip/hip_runtime.h>
#include <stdint.h>

typedef __attribute__((ext_vector_type(8))) short short8;
typedef __attribute__((ext_vector_type(4))) short short4v;
typedef __attribute__((ext_vector_type(4))) float floatx4;
typedef _Float16 half2v __attribute__((ext_vector_type(2)));

__device__ __forceinline__ float b2f(unsigned short u) {
  union { unsigned int i; float f; } v; v.i = ((unsigned int)u) << 16; return v.f;
}
__device__ __forceinline__ unsigned short f2b(float f) {
  union { float f; unsigned int i; } v; v.f = f;
  unsigned int i = v.i;
  return (unsigned short)((i + 0x7FFFu + ((i >> 16) & 1u)) >> 16);
}
__device__ __forceinline__ short4v pack4(float a, float b, float c, float d) {
  short4v r;
  r[0] = (short)f2b(a); r[1] = (short)f2b(b); r[2] = (short)f2b(c); r[3] = (short)f2b(d);
  return r;
}

// global -> LDS 16B per lane. lds_base wave-uniform; HW adds lane*16B.
__device__ __forceinline__ void stage16(const unsigned short* g, unsigned short* lds_base) {
  __builtin_amdgcn_global_load_lds((__attribute__((address_space(1))) const unsigned int*)g,
                                   (__attribute__((address_space(3))) unsigned int*)lds_base,
                                   16, 0, 0);
}

// ---------------------------------------------------------------------------
// r0/r7-verified 128x128 BK=32 engine (control).
// ---------------------------------------------------------------------------
template<int SYT, int SXT>
__global__ __launch_bounds__(256, 4) void gemm_bt(
    const unsigned short* __restrict__ A, const unsigned short* __restrict__ B,
    unsigned short* __restrict__ Cb, float* __restrict__ Cf,
    const float* __restrict__ rowdiv, const float* __restrict__ bias,
    int K, int lda, int ldb, int ldc,
    long long sA, long long sB, long long sC, long long sRD)
{
  const int tid  = threadIdx.x;
  const int lane = tid & 63;
  const int wave = tid >> 6;
  const int wr = wave >> 1, wc = wave & 1;
  int m0, n0;
  if constexpr (SYT > 0) {
    const int lin  = blockIdx.x;
    const int xcd  = lin & 7;
    const int rem  = lin >> 3;
    const int yloc = rem / SXT;
    const int x    = rem - yloc * SXT;
    m0 = (xcd * SYT + yloc) * 128;
    n0 = x * 128;
  } else {
    m0 = blockIdx.y * 128;
    n0 = blockIdx.x * 128;
  }
  const int bz = blockIdx.z;
  A += (long long)bz * sA;
  B += (long long)bz * sB;
  const float* rd = rowdiv ? rowdiv + (long long)bz * sRD : (const float*)0;

  __shared__ unsigned short As[128 * 32];
  __shared__ unsigned short Bs[128 * 32];

  floatx4 acc[4][4];
#pragma unroll
  for (int i = 0; i < 4; ++i)
#pragma unroll
    for (int j = 0; j < 4; ++j) acc[i][j] = floatx4{0.f, 0.f, 0.f, 0.f};

  const int t    = (lane & 7) ^ (lane >> 3);
  const int srow = 2 * (lane >> 3) + (t >> 2);
  const int scol = (t & 3) * 8;
  const unsigned short* ga0 = A + (long long)(m0 + wave * 32 + srow) * lda + scol;
  const unsigned short* ga1 = ga0 + 16LL * lda;
  const unsigned short* gb0 = B + (long long)(n0 + wave * 32 + srow) * ldb + scol;
  const unsigned short* gb1 = gb0 + 16LL * ldb;
  unsigned short* lA0 = As + wave * 1024;
  unsigned short* lA1 = lA0 + 512;
  unsigned short* lB0 = Bs + wave * 1024;
  unsigned short* lB1 = lB0 + 512;

  const int l15  = lane & 15;
  const int q    = lane >> 4;
  const int rofs = (l15 >> 1) * 64 + (((q + 4 * (l15 & 1)) ^ (l15 >> 1)) * 8);

  for (int kt = 0; kt < K; kt += 32) {
    __syncthreads();
    stage16(ga0 + kt, lA0);
    stage16(ga1 + kt, lA1);
    stage16(gb0 + kt, lB0);
    stage16(gb1 + kt, lB1);
    __syncthreads();
    short8 af[4], bfv[4];
#pragma unroll
    for (int i = 0; i < 4; ++i) af[i]  = *(const short8*)&As[(wr * 32 + i * 8) * 64 + rofs];
#pragma unroll
    for (int j = 0; j < 4; ++j) bfv[j] = *(const short8*)&Bs[(wc * 32 + j * 8) * 64 + rofs];
#pragma unroll
    for (int i = 0; i < 4; ++i)
#pragma unroll
      for (int j = 0; j < 4; ++j)
        acc[i][j] = __builtin_amdgcn_mfma_f32_16x16x32_bf16(bfv[j], af[i], acc[i][j], 0, 0, 0);
  }

#pragma unroll
  for (int i = 0; i < 4; ++i) {
    const int row = m0 + wr * 64 + i * 16 + l15;
    const float rcp = rd ? __builtin_amdgcn_rcpf(rd[row]) : 1.0f;
#pragma unroll
    for (int j = 0; j < 4; ++j) {
      const int colb = n0 + wc * 64 + j * 16 + q * 4;
      floatx4 v = acc[i][j];
      if (rd) { v[0] *= rcp; v[1] *= rcp; v[2] *= rcp; v[3] *= rcp; }
      if (bias) {
        const float4 bi = *(const float4*)&bias[colb];
        v[0] += bi.x; v[1] += bi.y; v[2] += bi.z; v[3] += bi.w;
      }
      if (Cb) *(short4v*)&Cb[(long long)bz * sC + (long long)row * ldc + colb] = pack4(v[0], v[1], v[2], v[3]);
      else    *(floatx4*)&Cf[(long long)bz * sC + (long long)row * ldc + colb] = v;
    }
  }
}

// ---------------------------------------------------------------------------
// DEEP 256x256 engine, ring-4, distance-3, 1 barrier + 32 MFMA per K-tile,
// counted vmcnt(8). FIXED vs r4: fragments in af8[8] (r4 overwrote af[4]
// between READ_A(0) and READ_A(4) before MFMA consumed them — plain register
// aliasing bug, not a pipeline race).
// Hazards (re-derived): stage at t -> buf[(t+3)&3]=buf[(t-1)&3] whose reads
// all waves consumed before their end-of-(t-1) barrier (compiler lgkmcnt
// before MFMA use); vmcnt(8) at end of t leaves exactly t+2/t+3's 8 loads
// outstanding => tile t+1 landed before the barrier opening iter t+1.
// ---------------------------------------------------------------------------
template<int SYT, int SXT>
__global__ __launch_bounds__(512, 1) void gemm256d(
    const unsigned short* __restrict__ A, const unsigned short* __restrict__ B,
    unsigned short* __restrict__ Cb, float* __restrict__ Cf,
    const float* __restrict__ rowdiv, const float* __restrict__ bias,
    int K, int lda, int ldb, int ldc,
    long long sA, long long sB, long long sC, long long sRD)
{
  const int tid  = threadIdx.x;
  const int lane = tid & 63;
  const int wave = tid >> 6;          // 0..7
  const int wr = wave >> 2;           // 0..1  (128-row half)
  const int wc = wave & 3;            // 0..3  (64-col quarter)
  int m0, n0;
  if constexpr (SYT > 0) {
    const int lin  = blockIdx.x;
    const int xcd  = lin & 7;
    const int rem  = lin >> 3;
    const int yloc = rem / SXT;
    const int x    = rem - yloc * SXT;
    m0 = (xcd * SYT + yloc) * 256;
    n0 = x * 256;
  } else {
    m0 = blockIdx.y * 256;
    n0 = blockIdx.x * 256;
  }
  const int bz = blockIdx.z;
  A += (long long)bz * sA;
  B += (long long)bz * sB;
  const float* rd = rowdiv ? rowdiv + (long long)bz * sRD : (const float*)0;

  __shared__ __align__(16) unsigned short lds[4 * 16384];   // ring-4, 128 KB

  floatx4 acc[8][4];
#pragma unroll
  for (int i = 0; i < 8; ++i)
#pragma unroll
    for (int j = 0; j < 4; ++j) acc[i][j] = floatx4{0.f, 0.f, 0.f, 0.f};

  const int t    = (lane & 7) ^ (lane >> 3);
  const int srow = 2 * (lane >> 3) + (t >> 2);
  const int scol = (t & 3) * 8;
  const unsigned short* ga0 = A + (long long)(m0 + wave * 32 + srow) * lda + scol;
  const unsigned short* ga1 = ga0 + 16LL * lda;
  const unsigned short* gb0 = B + (long long)(n0 + wave * 32 + srow) * ldb + scol;
  const unsigned short* gb1 = gb0 + 16LL * ldb;

  const int l15  = lane & 15;
  const int q    = lane >> 4;
  const int rofs = (l15 >> 1) * 64 + (((q + 4 * (l15 & 1)) ^ (l15 >> 1)) * 8);

  short8 af8[8], bfv[4];

  auto STAGE = [&](int kt, int buf) {     // 4 glds/wave: A then B
    unsigned short* dA = lds + buf * 16384 + wave * 1024;
    unsigned short* dB = dA + 8192;
    stage16(ga0 + kt, dA);
    stage16(ga1 + kt, dA + 512);
    stage16(gb0 + kt, dB);
    stage16(gb1 + kt, dB + 512);
  };
  auto READ_ALL = [&](int buf) {
    const unsigned short* Ab = lds + buf * 16384;
    const unsigned short* Bb = Ab + 8192;
#pragma unroll
    for (int j = 0; j < 4; ++j)
      bfv[j] = *(const short8*)&Bb[(wc * 32 + j * 8) * 64 + rofs];
#pragma unroll
    for (int i = 0; i < 8; ++i)
      af8[i] = *(const short8*)&Ab[(wr * 64 + i * 8) * 64 + rofs];
  };
  auto MFMA32 = [&]() {
#pragma unroll
    for (int i = 0; i < 8; ++i)
#pragma unroll
      for (int j = 0; j < 4; ++j)
        acc[i][j] = __builtin_amdgcn_mfma_f32_16x16x32_bf16(bfv[j], af8[i], acc[i][j], 0, 0, 0);
  };

  const int nt = K >> 5;                  // >= 4

  STAGE(0, 0);
  STAGE(32, 1);
  STAGE(64, 2);
  asm volatile("s_waitcnt vmcnt(8)" ::: "memory");   // tile 0 landed
  __builtin_amdgcn_s_barrier();

  for (int tt = 0; tt < nt; ++tt) {
    const int buf = tt & 3;
    if (tt + 3 < nt) STAGE((tt + 3) << 5, (tt + 3) & 3);
    READ_ALL(buf);
    __builtin_amdgcn_s_setprio(1);
    MFMA32();
    __builtin_amdgcn_s_setprio(0);
    if (tt < nt - 3)       { asm volatile("s_waitcnt vmcnt(8)" ::: "memory"); }
    else if (tt == nt - 3) { asm volatile("s_waitcnt vmcnt(4)" ::: "memory"); }
    else if (tt == nt - 2) { asm volatile("s_waitcnt vmcnt(0)" ::: "memory"); }
    if (tt + 1 < nt) __builtin_amdgcn_s_barrier();
  }

#pragma unroll
  for (int i = 0; i < 8; ++i) {
    const int row = m0 + wr * 128 + i * 16 + l15;
    const float rcp = rd ? __builtin_amdgcn_rcpf(rd[row]) : 1.0f;
#pragma unroll
    for (int j = 0; j < 4; ++j) {
      const int colb = n0 + wc * 64 + j * 16 + q * 4;
      floatx4 v = acc[i][j];
      if (rd) { v[0] *= rcp; v[1] *= rcp; v[2] *= rcp; v[3] *= rcp; }
      if (bias) {
        const float4 bi = *(const float4*)&bias[colb];
        v[0] += bi.x; v[1] += bi.y; v[2] += bi.z; v[3] += bi.w;
      }
      if (Cb) *(short4v*)&Cb[(long long)bz * sC + (long long)row * ldc + colb] = pack4(v[0], v[1], v[2], v[3]);
      else    *(floatx4*)&Cf[(long long)bz * sC + (long long)row * ldc + colb] = v;
    }
  }
}

// ---------------------------------------------------------------------------
// Fused scores + group + exp (verified r6/r7 form; qk rows 1536 wide).
// ---------------------------------------------------------------------------
__global__ __launch_bounds__(256) void score_weights(
    const unsigned short* __restrict__ qkv, const unsigned short* __restrict__ gw,
    unsigned short* __restrict__ Wout, float* __restrict__ L,
    const float* __restrict__ alpha)
{
  const int tid  = threadIdx.x;
  const int lane = tid & 63;
  const int wave = tid >> 6;
  const int wr = wave >> 1, wc = wave & 1;
  const int n0 = blockIdx.x * 128;
  const int m0 = blockIdx.y * 128;
  const int b  = blockIdx.z;

  const int l15 = lane & 15;
  const int q   = lane >> 4;
  const int q8  = q * 8;

  const unsigned short* gq = gw + ((long long)(b * 1024 + m0 + wr * 64)) * 64;
  const unsigned short* gk = gw + ((long long)(b * 1024 + n0 + wc * 64)) * 64;
  floatx4 gacc[4][4];
#pragma unroll
  for (int i = 0; i < 4; ++i)
#pragma unroll
    for (int j = 0; j < 4; ++j) gacc[i][j] = floatx4{0.f, 0.f, 0.f, 0.f};
#pragma unroll
  for (int ks = 0; ks < 2; ++ks) {
    short8 af[4], bfv[4];
#pragma unroll
    for (int i = 0; i < 4; ++i) af[i]  = *(const short8*)&gq[(long long)(i * 16 + l15) * 64 + ks * 32 + q8];
#pragma unroll
    for (int j = 0; j < 4; ++j) bfv[j] = *(const short8*)&gk[(long long)(j * 16 + l15) * 64 + ks * 32 + q8];
#pragma unroll
    for (int i = 0; i < 4; ++i)
#pragma unroll
      for (int j = 0; j < 4; ++j)
        gacc[i][j] = __builtin_amdgcn_mfma_f32_16x16x32_bf16(bfv[j], af[i], gacc[i][j], 0, 0, 0);
  }
  const float aa    = 1.0f / (1.0f + __expf(-alpha[0]));
  const float onema = 1.0f - aa;
  half2v gfp[4][4][2];
#pragma unroll
  for (int i = 0; i < 4; ++i)
#pragma unroll
    for (int j = 0; j < 4; ++j) {
      gfp[i][j][0] = half2v{(_Float16)(aa + onema * gacc[i][j][0]),
                            (_Float16)(aa + onema * gacc[i][j][1])};
      gfp[i][j][1] = half2v{(_Float16)(aa + onema * gacc[i][j][2]),
                            (_Float16)(aa + onema * gacc[i][j][3])};
    }

  const unsigned short* Aq = qkv + ((long long)(b * 1024 + m0)) * 1536;        // q cols 0..767
  const unsigned short* Bk = qkv + ((long long)(b * 1024 + n0)) * 1536 + 768;  // k cols 768..1535

  __shared__ unsigned short As[128 * 32];
  __shared__ unsigned short Bs[128 * 32];

  floatx4 sacc[4][4];
#pragma unroll
  for (int i = 0; i < 4; ++i)
#pragma unroll
    for (int j = 0; j < 4; ++j) sacc[i][j] = floatx4{0.f, 0.f, 0.f, 0.f};

  const int t    = (lane & 7) ^ (lane >> 3);
  const int srow = 2 * (lane >> 3) + (t >> 2);
  const int scol = (t & 3) * 8;
  const unsigned short* ga0 = Aq + (long long)(wave * 32 + srow) * 1536 + scol;
  const unsigned short* ga1 = ga0 + 16LL * 1536;
  const unsigned short* gb0 = Bk + (long long)(wave * 32 + srow) * 1536 + scol;
  const unsigned short* gb1 = gb0 + 16LL * 1536;
  unsigned short* lA0 = As + wave * 1024;
  unsigned short* lA1 = lA0 + 512;
  unsigned short* lB0 = Bs + wave * 1024;
  unsigned short* lB1 = lB0 + 512;

  const int rofs = (l15 >> 1) * 64 + (((q + 4 * (l15 & 1)) ^ (l15 >> 1)) * 8);

  for (int kt = 0; kt < 768; kt += 32) {
    __syncthreads();
    stage16(ga0 + kt, lA0);
    stage16(ga1 + kt, lA1);
    stage16(gb0 + kt, lB0);
    stage16(gb1 + kt, lB1);
    __syncthreads();
    short8 af[4], bfv[4];
#pragma unroll
    for (int i = 0; i < 4; ++i) af[i]  = *(const short8*)&As[(wr * 32 + i * 8) * 64 + rofs];
#pragma unroll
    for (int j = 0; j < 4; ++j) bfv[j] = *(const short8*)&Bs[(wc * 32 + j * 8) * 64 + rofs];
#pragma unroll
    for (int i = 0; i < 4; ++i)
#pragma unroll
      for (int j = 0; j < 4; ++j)
        sacc[i][j] = __builtin_amdgcn_mfma_f32_16x16x32_bf16(bfv[j], af[i], sacc[i][j], 0, 0, 0);
  }

  const float scale = 0.03608439182435161f;
  unsigned short* Wb = Wout + ((long long)b << 20);

#pragma unroll
  for (int i = 0; i < 4; ++i) {
    const int row = m0 + wr * 64 + i * 16 + l15;
    float ls = 0.0f;
#pragma unroll
    for (int j = 0; j < 4; ++j) {
      const int colb = n0 + wc * 64 + j * 16 + q * 4;
      float e0 = __expf(sacc[i][j][0] * scale);
      float e1 = __expf(sacc[i][j][1] * scale);
      float e2 = __expf(sacc[i][j][2] * scale);
      float e3 = __expf(sacc[i][j][3] * scale);
      ls += (e0 + e1) + (e2 + e3);
      *(short4v*)&Wb[(long long)row * 1024 + colb] =
        pack4(e0 * (float)gfp[i][j][0][0], e1 * (float)gfp[i][j][0][1],
              e2 * (float)gfp[i][j][1][0], e3 * (float)gfp[i][j][1][1]);
    }
    ls += __shfl_xor(ls, 16, 64);
    ls += __shfl_xor(ls, 32, 64);
    if (lane < 16) atomicAdd(&L[b * 1024 + row], ls);
  }
}

// ---------------------------------------------------------------------------
// MFMA-based gw (verified r5-r7; qk row stride 1536).
// ---------------------------------------------------------------------------
__global__ __launch_bounds__(256) void gw_mfma(
    const unsigned short* __restrict__ qkv, const unsigned short* __restrict__ Wgp64,
    unsigned short* __restrict__ gw)
{
  const int lane = threadIdx.x & 63;
  const int wave = threadIdx.x >> 6;
  const int l15  = lane & 15;
  const int q    = lane >> 4;
  const int q8   = q * 8;
  const long long row0 = (long long)blockIdx.x * 64 + wave * 16;
  const unsigned short* A = qkv + row0 * 1536;

  floatx4 acc[4];
#pragma unroll
  for (int j = 0; j < 4; ++j) acc[j] = floatx4{0.f, 0.f, 0.f, 0.f};

  for (int kt = 0; kt < 768; kt += 32) {
    short8 af = *(const short8*)&A[(long long)l15 * 1536 + kt + q8];
    short8 bf[4];
#pragma unroll
    for (int j = 0; j < 4; ++j)
      bf[j] = *(const short8*)&Wgp64[(j * 16 + l15) * 768 + kt + q8];
#pragma unroll
    for (int j = 0; j < 4; ++j)
      acc[j] = __builtin_amdgcn_mfma_f32_16x16x32_bf16(bf[j], af, acc[j], 0, 0, 0);
  }

  float mx = -1e30f;
#pragma unroll
  for (int j = 0; j < 4; ++j)
#pragma unroll
    for (int e = 0; e < 4; ++e) {
      const int col = j * 16 + q * 4 + e;
      if (col < 49) mx = fmaxf(mx, acc[j][e]);
    }
  mx = fmaxf(mx, __shfl_xor(mx, 16, 64));
  mx = fmaxf(mx, __shfl_xor(mx, 32, 64));

  float ev[4][4];
  float s = 0.0f;
#pragma unroll
  for (int j = 0; j < 4; ++j)
#pragma unroll
    for (int e = 0; e < 4; ++e) {
      const int col = j * 16 + q * 4 + e;
      const float x = (col < 49) ? __expf(acc[j][e] - mx) : 0.0f;
      ev[j][e] = x;
      s += x;
    }
  s += __shfl_xor(s, 16, 64);
  s += __shfl_xor(s, 32, 64);
  const float inv = 1.0f / s;

  unsigned short* out = gw + (row0 + l15) * 64;
#pragma unroll
  for (int j = 0; j < 4; ++j)
    *(short4v*)&out[j * 16 + q * 4] =
      pack4(ev[j][0] * inv, ev[j][1] * inv, ev[j][2] * inv, ev[j][3] * inv);
}

// ---------------------------------------------------------------------------
// 768x768x768 parallel GEMM for Wcomb (verified r7).
// ---------------------------------------------------------------------------
__global__ __launch_bounds__(256) void small_gemm_nt(
    const unsigned short* __restrict__ A, const unsigned short* __restrict__ B,
    unsigned short* __restrict__ C)
{
  const int lane = threadIdx.x & 63;
  const int wave = threadIdx.x >> 6;
  const int l15  = lane & 15;
  const int q    = lane >> 4;
  const int q8   = q * 8;
  const int rows0 = (blockIdx.y * 4 + wave) * 16;
  const int cols0 = blockIdx.x * 64;

  floatx4 acc[4];
#pragma unroll
  for (int j = 0; j < 4; ++j) acc[j] = floatx4{0.f, 0.f, 0.f, 0.f};

  for (int kt = 0; kt < 768; kt += 32) {
    short8 af = *(const short8*)&A[(rows0 + l15) * 768 + kt + q8];
    short8 bf[4];
#pragma unroll
    for (int j = 0; j < 4; ++j)
      bf[j] = *(const short8*)&B[(cols0 + j * 16 + l15) * 768 + kt + q8];
#pragma unroll
    for (int j = 0; j < 4; ++j)
      acc[j] = __builtin_amdgcn_mfma_f32_16x16x32_bf16(bf[j], af, acc[j], 0, 0, 0);
  }

  unsigned short* out = C + (rows0 + l15) * 768 + cols0;
#pragma unroll
  for (int j = 0; j < 4; ++j)
    *(short4v*)&out[j * 16 + q * 4] = pack4(acc[j][0], acc[j][1], acc[j][2], acc[j][3]);
}

__global__ void convert_f2b(const float* __restrict__ in, unsigned short* __restrict__ out, long long n)
{
  long long i = ((long long)blockIdx.x * 256 + threadIdx.x) * 4;
  if (i + 3 >= n) {
    for (long long k = i; k < n; ++k) out[k] = f2b(in[k]);
    return;
  }
  float4 v = *(const float4*)(in + i);
  out[i + 0] = f2b(v.x);
  out[i + 1] = f2b(v.y);
  out[i + 2] = f2b(v.z);
  out[i + 3] = f2b(v.w);
}

__global__ void transpose_f2b(const float* __restrict__ in, unsigned short* __restrict__ out,
                              int R, int C, int ldin, int ldout)
{
  __shared__ unsigned short t[32][33];
  const int c0 = blockIdx.x * 32, r0 = blockIdx.y * 32;
  for (int i = threadIdx.y; i < 32; i += 8) {
    const int r = r0 + i, c = c0 + threadIdx.x;
    if (r < R && c < C) t[i][threadIdx.x] = f2b(in[(long long)r * ldin + c]);
  }
  __syncthreads();
  for (int i = threadIdx.y; i < 32; i += 8) {
    const int r = c0 + i, c = r0 + threadIdx.x;
    if (r < C && c < R) out[(long long)r * ldout + c] = t[threadIdx.x][i];
  }
}

// WvB[768][768] bf16 = W_qkv[:, 1536:2304]
__global__ void slice_f2b(const float* __restrict__ in, unsigned short* __restrict__ out)
{
  const long long idx = (long long)blockIdx.x * 256 + threadIdx.x;
  const int r = (int)(idx / 768), c = (int)(idx - (long long)r * 768);
  out[idx] = f2b(in[(long long)r * 2304 + 1536 + c]);
}

// bias2[j] = b_proj[j] + sum_d WprojT[j][d] * b_qkv[1536+d]  (verified r7)
__global__ __launch_bounds__(256) void bias2_kernel(
    const unsigned short* __restrict__ WprojT, const float* __restrict__ b_qkv,
    const float* __restrict__ b_proj, float* __restrict__ bias2)
{
  const int lane = threadIdx.x & 63;
  const int wave = threadIdx.x >> 6;
  const int j = blockIdx.x * 4 + wave;
  float s = 0.0f;
#pragma unroll
  for (int tt = 0; tt < 12; ++tt) {
    const int d = tt * 64 + lane;
    s += b2f(WprojT[j * 768 + d]) * b_qkv[1536 + d];
  }
#pragma unroll
  for (int m = 1; m < 64; m <<= 1) s += __shfl_xor(s, m, 64);
  if (lane == 0) bias2[j] = b_proj[j] + s;
}

extern "C" void kernel_launch(void* const* d_in, const int* in_sizes, int n_in,
                              void* d_out, int out_size, void* d_ws, size_t ws_size,
                              hipStream_t stream)
{
  const float* x      = (const float*)d_in[0];
  const float* W_qkv  = (const float*)d_in[1];
  const float* b_qkv  = (const float*)d_in[2];
  const float* W_proj = (const float*)d_in[3];
  const float* b_proj = (const float*)d_in[4];
  const float* W_gp   = (const float*)d_in[5];
  const float* alpha  = (const float*)d_in[6];

  char* p = (char*)d_ws;
  auto alloc = [&](size_t bytes) { char* r = p; p += (bytes + 255) & ~255ULL; return r; };
  unsigned short* qk     = (unsigned short*)alloc(16384ULL * 1536 * 2);
  unsigned short* xb     = (unsigned short*)alloc(16384ULL * 768 * 2);
  unsigned short* WqkvT  = (unsigned short*)alloc(1536ULL * 768 * 2);
  unsigned short* WprojT = (unsigned short*)alloc(768ULL * 768 * 2);
  unsigned short* WvB    = (unsigned short*)alloc(768ULL * 768 * 2);
  unsigned short* Wcomb  = (unsigned short*)alloc(768ULL * 768 * 2);
  unsigned short* Wgp64  = (unsigned short*)alloc(64ULL * 768 * 2);
  unsigned short* gwbuf  = (unsigned short*)alloc(16384ULL * 64 * 2);
  float*          Lbuf   = (float*)alloc(16384ULL * 4);
  float*          bias2  = (float*)alloc(768ULL * 4);
  unsigned short* wmat   = (unsigned short*)alloc(16ULL * 1024 * 1024 * 2);
  unsigned short* vpT    = (unsigned short*)alloc(16ULL * 768 * 1024 * 2);

  const dim3 blk256(256);
  const dim3 blk512(512);
  const dim3 tb(32, 8);

  convert_f2b<<<dim3(12288), blk256, 0, stream>>>(x, xb, 16384LL * 768);
  transpose_f2b<<<dim3(48, 24), tb, 0, stream>>>(W_qkv, WqkvT, 768, 1536, 2304, 768);
  transpose_f2b<<<dim3(24, 24), tb, 0, stream>>>(W_proj, WprojT, 768, 768, 768, 768);
  hipMemsetAsync(Wgp64, 0, 64ULL * 768 * 2, stream);
  transpose_f2b<<<dim3(2, 24), tb, 0, stream>>>(W_gp, Wgp64, 768, 49, 49, 768);
  slice_f2b<<<dim3(2304), blk256, 0, stream>>>(W_qkv, WvB);

  small_gemm_nt<<<dim3(12, 12), blk256, 0, stream>>>(WprojT, WvB, Wcomb);
  bias2_kernel<<<dim3(192), blk256, 0, stream>>>(WprojT, b_qkv, b_proj, bias2);

  // qk = x @ W_qkv[:, :1536] + b_qkv[:1536]  -- A/B probe:
  // rows 0..8191: control 128² engine (768 blocks = 8 xcd * 8 y * 12 x)
  gemm_bt<8, 12><<<dim3(768, 1, 1), blk256, 0, stream>>>(xb, WqkvT, qk, (float*)0,
                                                         (const float*)0, b_qkv,
                                                         768, 768, 768, 1536, 0, 0, 0, 0);
  // rows 8192..16383: DEEP 256² engine (192 blocks = 8 xcd * 4 y * 6 x)
  gemm256d<4, 6><<<dim3(192, 1, 1), blk512, 0, stream>>>(xb + 8192LL * 768, WqkvT,
                                                         qk + 8192LL * 1536, (float*)0,
                                                         (const float*)0, b_qkv,
                                                         768, 768, 768, 1536, 0, 0, 0, 0);

  gw_mfma<<<dim3(256), blk256, 0, stream>>>(qk, Wgp64, gwbuf);

  hipMemsetAsync(Lbuf, 0, 16384 * 4, stream);

  score_weights<<<dim3(8, 8, 16), blk256, 0, stream>>>(qk, gwbuf, wmat, Lbuf, alpha);

  // vpT[b][j][m] = sum_k Wcomb[j][k] * x[b][m][k]
  gemm_bt<0, 0><<<dim3(8, 6, 16), blk256, 0, stream>>>(Wcomb, xb, vpT, (float*)0,
                                                       (const float*)0, (const float*)0,
                                                       768, 768, 768, 1024,
                                                       0, 1024LL * 768, 768LL * 1024, 0);

  // out[m][j] = (1/L[m]) * sum_n wmat[m][n] * vpT[j][n] + bias2[j]
  gemm_bt<0, 0><<<dim3(6, 8, 16), blk256, 0, stream>>>(wmat, vpT, (unsigned short*)0, (float*)d_out,
                                                       Lbuf, bias2,
                                                       1024, 1024, 1024, 768,
                                                       1024LL * 1024, 768LL * 1024, 1024LL * 768, 1024);
}

// Round 9
// 360.940 us; speedup vs baseline: 1.0346x; 1.0346x over previous
//
#include <hip/hip_runtime.h>
#include <stdint.h>

typedef __attribute__((ext_vector_type(8))) short short8;
typedef __attribute__((ext_vector_type(4))) short short4v;
typedef __attribute__((ext_vector_type(4))) float floatx4;
typedef _Float16 half2v __attribute__((ext_vector_type(2)));

__device__ __forceinline__ float b2f(unsigned short u) {
  union { unsigned int i; float f; } v; v.i = ((unsigned int)u) << 16; return v.f;
}
__device__ __forceinline__ unsigned short f2b(float f) {
  union { float f; unsigned int i; } v; v.f = f;
  unsigned int i = v.i;
  return (unsigned short)((i + 0x7FFFu + ((i >> 16) & 1u)) >> 16);
}
__device__ __forceinline__ short4v pack4(float a, float b, float c, float d) {
  short4v r;
  r[0] = (short)f2b(a); r[1] = (short)f2b(b); r[2] = (short)f2b(c); r[3] = (short)f2b(d);
  return r;
}

// global -> LDS 16B per lane. lds_base wave-uniform; HW adds lane*16B.
__device__ __forceinline__ void stage16(const unsigned short* g, unsigned short* lds_base) {
  __builtin_amdgcn_global_load_lds((__attribute__((address_space(1))) const unsigned int*)g,
                                   (__attribute__((address_space(3))) unsigned int*)lds_base,
                                   16, 0, 0);
}

// ---------------------------------------------------------------------------
// r0/r7-verified 128x128 BK=32 engine. ~565 TF at these shapes; r8's A/B
// proved the deep-pipeline 256² variant is 18% SLOWER (1 blk/CU kills TLP)
// — schedule levers exhausted, this engine is the session GEMM ceiling.
// ---------------------------------------------------------------------------
template<int SYT, int SXT>
__global__ __launch_bounds__(256, 4) void gemm_bt(
    const unsigned short* __restrict__ A, const unsigned short* __restrict__ B,
    unsigned short* __restrict__ Cb, float* __restrict__ Cf,
    const float* __restrict__ rowdiv, const float* __restrict__ bias,
    int K, int lda, int ldb, int ldc,
    long long sA, long long sB, long long sC, long long sRD)
{
  const int tid  = threadIdx.x;
  const int lane = tid & 63;
  const int wave = tid >> 6;
  const int wr = wave >> 1, wc = wave & 1;
  int m0, n0;
  if constexpr (SYT > 0) {
    const int lin  = blockIdx.x;
    const int xcd  = lin & 7;
    const int rem  = lin >> 3;
    const int yloc = rem / SXT;
    const int x    = rem - yloc * SXT;
    m0 = (xcd * SYT + yloc) * 128;
    n0 = x * 128;
  } else {
    m0 = blockIdx.y * 128;
    n0 = blockIdx.x * 128;
  }
  const int bz = blockIdx.z;
  A += (long long)bz * sA;
  B += (long long)bz * sB;
  const float* rd = rowdiv ? rowdiv + (long long)bz * sRD : (const float*)0;

  __shared__ unsigned short As[128 * 32];
  __shared__ unsigned short Bs[128 * 32];

  floatx4 acc[4][4];
#pragma unroll
  for (int i = 0; i < 4; ++i)
#pragma unroll
    for (int j = 0; j < 4; ++j) acc[i][j] = floatx4{0.f, 0.f, 0.f, 0.f};

  const int t    = (lane & 7) ^ (lane >> 3);
  const int srow = 2 * (lane >> 3) + (t >> 2);
  const int scol = (t & 3) * 8;
  const unsigned short* ga0 = A + (long long)(m0 + wave * 32 + srow) * lda + scol;
  const unsigned short* ga1 = ga0 + 16LL * lda;
  const unsigned short* gb0 = B + (long long)(n0 + wave * 32 + srow) * ldb + scol;
  const unsigned short* gb1 = gb0 + 16LL * ldb;
  unsigned short* lA0 = As + wave * 1024;
  unsigned short* lA1 = lA0 + 512;
  unsigned short* lB0 = Bs + wave * 1024;
  unsigned short* lB1 = lB0 + 512;

  const int l15  = lane & 15;
  const int q    = lane >> 4;
  const int rofs = (l15 >> 1) * 64 + (((q + 4 * (l15 & 1)) ^ (l15 >> 1)) * 8);

  for (int kt = 0; kt < K; kt += 32) {
    __syncthreads();
    stage16(ga0 + kt, lA0);
    stage16(ga1 + kt, lA1);
    stage16(gb0 + kt, lB0);
    stage16(gb1 + kt, lB1);
    __syncthreads();
    short8 af[4], bfv[4];
#pragma unroll
    for (int i = 0; i < 4; ++i) af[i]  = *(const short8*)&As[(wr * 32 + i * 8) * 64 + rofs];
#pragma unroll
    for (int j = 0; j < 4; ++j) bfv[j] = *(const short8*)&Bs[(wc * 32 + j * 8) * 64 + rofs];
#pragma unroll
    for (int i = 0; i < 4; ++i)
#pragma unroll
      for (int j = 0; j < 4; ++j)
        acc[i][j] = __builtin_amdgcn_mfma_f32_16x16x32_bf16(bfv[j], af[i], acc[i][j], 0, 0, 0);
  }

#pragma unroll
  for (int i = 0; i < 4; ++i) {
    const int row = m0 + wr * 64 + i * 16 + l15;
    const float rcp = rd ? __builtin_amdgcn_rcpf(rd[row]) : 1.0f;
#pragma unroll
    for (int j = 0; j < 4; ++j) {
      const int colb = n0 + wc * 64 + j * 16 + q * 4;
      floatx4 v = acc[i][j];
      if (rd) { v[0] *= rcp; v[1] *= rcp; v[2] *= rcp; v[3] *= rcp; }
      if (bias) {
        const float4 bi = *(const float4*)&bias[colb];
        v[0] += bi.x; v[1] += bi.y; v[2] += bi.z; v[3] += bi.w;
      }
      if (Cb) *(short4v*)&Cb[(long long)bz * sC + (long long)row * ldc + colb] = pack4(v[0], v[1], v[2], v[3]);
      else    *(floatx4*)&Cf[(long long)bz * sC + (long long)row * ldc + colb] = v;
    }
  }
}

// ---------------------------------------------------------------------------
// Fused scores + group + exp. r9: rectangular XCD swizzle — per batch the
// 64 blocks map so XCD j (= blockIdx.x, since linear id % 8 = x) owns a
// 2m x 4n tile rectangle: q 0.39MB + k 0.78MB = 1.17 MB/batch/XCD (was
// 1 n-stripe x all m = 1.77 MB). Bijective: m=(bx>>1)*2+(by>>2),
// n=(bx&1)*4+(by&3).
// ---------------------------------------------------------------------------
__global__ __launch_bounds__(256) void score_weights(
    const unsigned short* __restrict__ qkv, const unsigned short* __restrict__ gw,
    unsigned short* __restrict__ Wout, float* __restrict__ L,
    const float* __restrict__ alpha)
{
  const int tid  = threadIdx.x;
  const int lane = tid & 63;
  const int wave = tid >> 6;
  const int wr = wave >> 1, wc = wave & 1;
  const int bx = blockIdx.x;             // == xcd
  const int by = blockIdx.y;
  const int m0 = ((bx >> 1) * 2 + (by >> 2)) * 128;
  const int n0 = ((bx & 1) * 4 + (by & 3)) * 128;
  const int b  = blockIdx.z;

  const int l15 = lane & 15;
  const int q   = lane >> 4;
  const int q8  = q * 8;

  const unsigned short* gq = gw + ((long long)(b * 1024 + m0 + wr * 64)) * 64;
  const unsigned short* gk = gw + ((long long)(b * 1024 + n0 + wc * 64)) * 64;
  floatx4 gacc[4][4];
#pragma unroll
  for (int i = 0; i < 4; ++i)
#pragma unroll
    for (int j = 0; j < 4; ++j) gacc[i][j] = floatx4{0.f, 0.f, 0.f, 0.f};
#pragma unroll
  for (int ks = 0; ks < 2; ++ks) {
    short8 af[4], bfv[4];
#pragma unroll
    for (int i = 0; i < 4; ++i) af[i]  = *(const short8*)&gq[(long long)(i * 16 + l15) * 64 + ks * 32 + q8];
#pragma unroll
    for (int j = 0; j < 4; ++j) bfv[j] = *(const short8*)&gk[(long long)(j * 16 + l15) * 64 + ks * 32 + q8];
#pragma unroll
    for (int i = 0; i < 4; ++i)
#pragma unroll
      for (int j = 0; j < 4; ++j)
        gacc[i][j] = __builtin_amdgcn_mfma_f32_16x16x32_bf16(bfv[j], af[i], gacc[i][j], 0, 0, 0);
  }
  const float aa    = 1.0f / (1.0f + __expf(-alpha[0]));
  const float onema = 1.0f - aa;
  half2v gfp[4][4][2];
#pragma unroll
  for (int i = 0; i < 4; ++i)
#pragma unroll
    for (int j = 0; j < 4; ++j) {
      gfp[i][j][0] = half2v{(_Float16)(aa + onema * gacc[i][j][0]),
                            (_Float16)(aa + onema * gacc[i][j][1])};
      gfp[i][j][1] = half2v{(_Float16)(aa + onema * gacc[i][j][2]),
                            (_Float16)(aa + onema * gacc[i][j][3])};
    }

  const unsigned short* Aq = qkv + ((long long)(b * 1024 + m0)) * 1536;        // q cols 0..767
  const unsigned short* Bk = qkv + ((long long)(b * 1024 + n0)) * 1536 + 768;  // k cols 768..1535

  __shared__ unsigned short As[128 * 32];
  __shared__ unsigned short Bs[128 * 32];

  floatx4 sacc[4][4];
#pragma unroll
  for (int i = 0; i < 4; ++i)
#pragma unroll
    for (int j = 0; j < 4; ++j) sacc[i][j] = floatx4{0.f, 0.f, 0.f, 0.f};

  const int t    = (lane & 7) ^ (lane >> 3);
  const int srow = 2 * (lane >> 3) + (t >> 2);
  const int scol = (t & 3) * 8;
  const unsigned short* ga0 = Aq + (long long)(wave * 32 + srow) * 1536 + scol;
  const unsigned short* ga1 = ga0 + 16LL * 1536;
  const unsigned short* gb0 = Bk + (long long)(wave * 32 + srow) * 1536 + scol;
  const unsigned short* gb1 = gb0 + 16LL * 1536;
  unsigned short* lA0 = As + wave * 1024;
  unsigned short* lA1 = lA0 + 512;
  unsigned short* lB0 = Bs + wave * 1024;
  unsigned short* lB1 = lB0 + 512;

  const int rofs = (l15 >> 1) * 64 + (((q + 4 * (l15 & 1)) ^ (l15 >> 1)) * 8);

  for (int kt = 0; kt < 768; kt += 32) {
    __syncthreads();
    stage16(ga0 + kt, lA0);
    stage16(ga1 + kt, lA1);
    stage16(gb0 + kt, lB0);
    stage16(gb1 + kt, lB1);
    __syncthreads();
    short8 af[4], bfv[4];
#pragma unroll
    for (int i = 0; i < 4; ++i) af[i]  = *(const short8*)&As[(wr * 32 + i * 8) * 64 + rofs];
#pragma unroll
    for (int j = 0; j < 4; ++j) bfv[j] = *(const short8*)&Bs[(wc * 32 + j * 8) * 64 + rofs];
#pragma unroll
    for (int i = 0; i < 4; ++i)
#pragma unroll
      for (int j = 0; j < 4; ++j)
        sacc[i][j] = __builtin_amdgcn_mfma_f32_16x16x32_bf16(bfv[j], af[i], sacc[i][j], 0, 0, 0);
  }

  const float scale = 0.03608439182435161f;
  unsigned short* Wb = Wout + ((long long)b << 20);

#pragma unroll
  for (int i = 0; i < 4; ++i) {
    const int row = m0 + wr * 64 + i * 16 + l15;
    float ls = 0.0f;
#pragma unroll
    for (int j = 0; j < 4; ++j) {
      const int colb = n0 + wc * 64 + j * 16 + q * 4;
      float e0 = __expf(sacc[i][j][0] * scale);
      float e1 = __expf(sacc[i][j][1] * scale);
      float e2 = __expf(sacc[i][j][2] * scale);
      float e3 = __expf(sacc[i][j][3] * scale);
      ls += (e0 + e1) + (e2 + e3);
      *(short4v*)&Wb[(long long)row * 1024 + colb] =
        pack4(e0 * (float)gfp[i][j][0][0], e1 * (float)gfp[i][j][0][1],
              e2 * (float)gfp[i][j][1][0], e3 * (float)gfp[i][j][1][1]);
    }
    ls += __shfl_xor(ls, 16, 64);
    ls += __shfl_xor(ls, 32, 64);
    if (lane < 16) atomicAdd(&L[b * 1024 + row], ls);
  }
}

// ---------------------------------------------------------------------------
// MFMA-based gw (verified r5-r8). r9: also zero-inits L (drops a memset
// dispatch; gw always runs before score_weights).
// ---------------------------------------------------------------------------
__global__ __launch_bounds__(256) void gw_mfma(
    const unsigned short* __restrict__ qkv, const unsigned short* __restrict__ Wgp64,
    unsigned short* __restrict__ gw, float* __restrict__ L)
{
  const int lane = threadIdx.x & 63;
  const int wave = threadIdx.x >> 6;
  const int l15  = lane & 15;
  const int q    = lane >> 4;
  const int q8   = q * 8;
  const long long row0 = (long long)blockIdx.x * 64 + wave * 16;
  const unsigned short* A = qkv + row0 * 1536;

  if (q == 0) L[row0 + l15] = 0.0f;   // covers all 16384 rows exactly once

  floatx4 acc[4];
#pragma unroll
  for (int j = 0; j < 4; ++j) acc[j] = floatx4{0.f, 0.f, 0.f, 0.f};

  for (int kt = 0; kt < 768; kt += 32) {
    short8 af = *(const short8*)&A[(long long)l15 * 1536 + kt + q8];
    short8 bf[4];
#pragma unroll
    for (int j = 0; j < 4; ++j)
      bf[j] = *(const short8*)&Wgp64[(j * 16 + l15) * 768 + kt + q8];
#pragma unroll
    for (int j = 0; j < 4; ++j)
      acc[j] = __builtin_amdgcn_mfma_f32_16x16x32_bf16(bf[j], af, acc[j], 0, 0, 0);
  }

  float mx = -1e30f;
#pragma unroll
  for (int j = 0; j < 4; ++j)
#pragma unroll
    for (int e = 0; e < 4; ++e) {
      const int col = j * 16 + q * 4 + e;
      if (col < 49) mx = fmaxf(mx, acc[j][e]);
    }
  mx = fmaxf(mx, __shfl_xor(mx, 16, 64));
  mx = fmaxf(mx, __shfl_xor(mx, 32, 64));

  float ev[4][4];
  float s = 0.0f;
#pragma unroll
  for (int j = 0; j < 4; ++j)
#pragma unroll
    for (int e = 0; e < 4; ++e) {
      const int col = j * 16 + q * 4 + e;
      const float x = (col < 49) ? __expf(acc[j][e] - mx) : 0.0f;
      ev[j][e] = x;
      s += x;
    }
  s += __shfl_xor(s, 16, 64);
  s += __shfl_xor(s, 32, 64);
  const float inv = 1.0f / s;

  unsigned short* out = gw + (row0 + l15) * 64;
#pragma unroll
  for (int j = 0; j < 4; ++j)
    *(short4v*)&out[j * 16 + q * 4] =
      pack4(ev[j][0] * inv, ev[j][1] * inv, ev[j][2] * inv, ev[j][3] * inv);
}

// ---------------------------------------------------------------------------
// 768x768x768 parallel GEMM for Wcomb (verified r7/r8).
// ---------------------------------------------------------------------------
__global__ __launch_bounds__(256) void small_gemm_nt(
    const unsigned short* __restrict__ A, const unsigned short* __restrict__ B,
    unsigned short* __restrict__ C)
{
  const int lane = threadIdx.x & 63;
  const int wave = threadIdx.x >> 6;
  const int l15  = lane & 15;
  const int q    = lane >> 4;
  const int q8   = q * 8;
  const int rows0 = (blockIdx.y * 4 + wave) * 16;
  const int cols0 = blockIdx.x * 64;

  floatx4 acc[4];
#pragma unroll
  for (int j = 0; j < 4; ++j) acc[j] = floatx4{0.f, 0.f, 0.f, 0.f};

  for (int kt = 0; kt < 768; kt += 32) {
    short8 af = *(const short8*)&A[(rows0 + l15) * 768 + kt + q8];
    short8 bf[4];
#pragma unroll
    for (int j = 0; j < 4; ++j)
      bf[j] = *(const short8*)&B[(cols0 + j * 16 + l15) * 768 + kt + q8];
#pragma unroll
    for (int j = 0; j < 4; ++j)
      acc[j] = __builtin_amdgcn_mfma_f32_16x16x32_bf16(bf[j], af, acc[j], 0, 0, 0);
  }

  unsigned short* out = C + (rows0 + l15) * 768 + cols0;
#pragma unroll
  for (int j = 0; j < 4; ++j)
    *(short4v*)&out[j * 16 + q * 4] = pack4(acc[j][0], acc[j][1], acc[j][2], acc[j][3]);
}

// grid-stride fp32 -> bf16, 16B stores (n must be a multiple of 8).
__global__ void convert_f2b(const float* __restrict__ in, unsigned short* __restrict__ out, long long n)
{
  const long long stride = (long long)gridDim.x * blockDim.x * 8;
  for (long long i = ((long long)blockIdx.x * blockDim.x + threadIdx.x) * 8; i < n; i += stride) {
    const float4 a = *(const float4*)(in + i);
    const float4 b = *(const float4*)(in + i + 4);
    short8 r;
    r[0] = (short)f2b(a.x); r[1] = (short)f2b(a.y); r[2] = (short)f2b(a.z); r[3] = (short)f2b(a.w);
    r[4] = (short)f2b(b.x); r[5] = (short)f2b(b.y); r[6] = (short)f2b(b.z); r[7] = (short)f2b(b.w);
    *(short8*)(out + i) = r;
  }
}

// transpose fp32[R][C] -> bf16[Rpad][R] (out row r = input col r); rows
// C..Rpad-1 written as zeros (folds the Wgp64 zero-pad memset in).
__global__ void transpose_f2b(const float* __restrict__ in, unsigned short* __restrict__ out,
                              int R, int C, int ldin, int ldout, int Rpad)
{
  __shared__ unsigned short t[32][33];
  const int c0 = blockIdx.x * 32, r0 = blockIdx.y * 32;
  for (int i = threadIdx.y; i < 32; i += 8) {
    const int r = r0 + i, c = c0 + threadIdx.x;
    if (r < R && c < C) t[i][threadIdx.x] = f2b(in[(long long)r * ldin + c]);
  }
  __syncthreads();
  for (int i = threadIdx.y; i < 32; i += 8) {
    const int r = c0 + i, c = r0 + threadIdx.x;
    if (r < Rpad && c < R) {
      unsigned short v = 0;
      if (r < C) v = t[threadIdx.x][i];
      out[(long long)r * ldout + c] = v;
    }
  }
}

// WvB[768][768] bf16 = W_qkv[:, 1536:2304]
__global__ void slice_f2b(const float* __restrict__ in, unsigned short* __restrict__ out)
{
  const long long idx = (long long)blockIdx.x * 256 + threadIdx.x;
  const int r = (int)(idx / 768), c = (int)(idx - (long long)r * 768);
  out[idx] = f2b(in[(long long)r * 2304 + 1536 + c]);
}

// bias2[j] = b_proj[j] + sum_d WprojT[j][d] * b_qkv[1536+d]  (verified r7/r8)
__global__ __launch_bounds__(256) void bias2_kernel(
    const unsigned short* __restrict__ WprojT, const float* __restrict__ b_qkv,
    const float* __restrict__ b_proj, float* __restrict__ bias2)
{
  const int lane = threadIdx.x & 63;
  const int wave = threadIdx.x >> 6;
  const int j = blockIdx.x * 4 + wave;
  float s = 0.0f;
#pragma unroll
  for (int tt = 0; tt < 12; ++tt) {
    const int d = tt * 64 + lane;
    s += b2f(WprojT[j * 768 + d]) * b_qkv[1536 + d];
  }
#pragma unroll
  for (int m = 1; m < 64; m <<= 1) s += __shfl_xor(s, m, 64);
  if (lane == 0) bias2[j] = b_proj[j] + s;
}

extern "C" void kernel_launch(void* const* d_in, const int* in_sizes, int n_in,
                              void* d_out, int out_size, void* d_ws, size_t ws_size,
                              hipStream_t stream)
{
  const float* x      = (const float*)d_in[0];
  const float* W_qkv  = (const float*)d_in[1];
  const float* b_qkv  = (const float*)d_in[2];
  const float* W_proj = (const float*)d_in[3];
  const float* b_proj = (const float*)d_in[4];
  const float* W_gp   = (const float*)d_in[5];
  const float* alpha  = (const float*)d_in[6];

  char* p = (char*)d_ws;
  auto alloc = [&](size_t bytes) { char* r = p; p += (bytes + 255) & ~255ULL; return r; };
  unsigned short* qk     = (unsigned short*)alloc(16384ULL * 1536 * 2);
  unsigned short* xb     = (unsigned short*)alloc(16384ULL * 768 * 2);
  unsigned short* WqkvT  = (unsigned short*)alloc(1536ULL * 768 * 2);
  unsigned short* WprojT = (unsigned short*)alloc(768ULL * 768 * 2);
  unsigned short* WvB    = (unsigned short*)alloc(768ULL * 768 * 2);
  unsigned short* Wcomb  = (unsigned short*)alloc(768ULL * 768 * 2);
  unsigned short* Wgp64  = (unsigned short*)alloc(64ULL * 768 * 2);
  unsigned short* gwbuf  = (unsigned short*)alloc(16384ULL * 64 * 2);
  float*          Lbuf   = (float*)alloc(16384ULL * 4);
  float*          bias2  = (float*)alloc(768ULL * 4);
  unsigned short* wmat   = (unsigned short*)alloc(16ULL * 1024 * 1024 * 2);
  unsigned short* vpT    = (unsigned short*)alloc(16ULL * 768 * 1024 * 2);

  const dim3 blk256(256);
  const dim3 tb(32, 8);

  // prep: 7 dispatches (was 9 + 2 memsets)
  convert_f2b<<<dim3(2048), blk256, 0, stream>>>(x, xb, 16384LL * 768);
  transpose_f2b<<<dim3(48, 24), tb, 0, stream>>>(W_qkv, WqkvT, 768, 1536, 2304, 768, 1536);
  transpose_f2b<<<dim3(24, 24), tb, 0, stream>>>(W_proj, WprojT, 768, 768, 768, 768, 768);
  transpose_f2b<<<dim3(2, 24), tb, 0, stream>>>(W_gp, Wgp64, 768, 49, 49, 768, 64);  // zero-pads 49..63
  slice_f2b<<<dim3(2304), blk256, 0, stream>>>(W_qkv, WvB);
  small_gemm_nt<<<dim3(12, 12), blk256, 0, stream>>>(WprojT, WvB, Wcomb);
  bias2_kernel<<<dim3(192), blk256, 0, stream>>>(WprojT, b_qkv, b_proj, bias2);

  // qk = x @ W_qkv[:, :1536] + b_qkv[:1536]  (r7 config: 1536 = 8*16*12)
  gemm_bt<16, 12><<<dim3(1536, 1, 1), blk256, 0, stream>>>(xb, WqkvT, qk, (float*)0,
                                                           (const float*)0, b_qkv,
                                                           768, 768, 768, 1536, 0, 0, 0, 0);

  // gw = softmax(q @ W_gp) (also zero-inits L)
  gw_mfma<<<dim3(256), blk256, 0, stream>>>(qk, Wgp64, gwbuf, Lbuf);

  // weights (unnormalized) + L  (rect XCD swizzle)
  score_weights<<<dim3(8, 8, 16), blk256, 0, stream>>>(qk, gwbuf, wmat, Lbuf, alpha);

  // vpT[b][j][m] = sum_k Wcomb[j][k] * x[b][m][k]
  gemm_bt<0, 0><<<dim3(8, 6, 16), blk256, 0, stream>>>(Wcomb, xb, vpT, (float*)0,
                                                       (const float*)0, (const float*)0,
                                                       768, 768, 768, 1024,
                                                       0, 1024LL * 768, 768LL * 1024, 0);

  // out[m][j] = (1/L[m]) * sum_n wmat[m][n] * vpT[j][n] + bias2[j]
  gemm_bt<0, 0><<<dim3(6, 8, 16), blk256, 0, stream>>>(wmat, vpT, (unsigned short*)0, (float*)d_out,
                                                       Lbuf, bias2,
                                                       1024, 1024, 1024, 768,
                                                       1024LL * 1024, 768LL * 1024, 1024LL * 768, 1024);
}